// Round 4
// baseline (376.223 us; speedup 1.0000x reference)
//
#include <hip/hip_runtime.h>

// DynamicMultiRNN: 2-layer shared-weight LSTM, B=1024 T=200 D=128, residual on L2.
// f32 I/O, bf16 MFMA internals.
//
// R9: GATE-SPLIT WAVE PAIRS -> 4 waves/SIMD (was 2).
//  R8's wall: 2746 cyc/iter vs ~1400 of issue work — latency/contention with
//  only 2 waves/SIMD, pinned there because a 4-col-tile wave needs Breg=128
//  regs (VGPR 108 + AGPR ~128 = 256-reg class). Fix: 16 waves/block, each
//  wave owns 2 col-tiles (Breg=64) -> total ~120 regs -> launch_bounds(1024,4)
//  = 4 waves/SIMD. Gates split across wave pairs:
//    role 0 (waves 0-7):  gates i,f  -> sig(i),sig(f) -> LDS exchange buf ZX
//    role 1 (waves 8-15): gates g,o  -> after barrier#2: read ZX, serial tail
//                         (cn, tanh, hn), ALL state + LDS h-writes + out.
//  role 0 fills its post-exchange slot with x staging/prefetch.
//  Per-CU MFMA (256/iter), trans, LDS-A traffic unchanged — pure TLP win.
//  role = w>>3 so each SIMD gets 2 role-0 + 2 role-1 waves (w%4 round-robin).
//
// PACKED A-TILE (8 x 256, RS=264), same as R8:
// rows 0-3 = [x_b(i)     | h1_b(i-1)]   L1 inputs, batch rows b=0..3
// rows 4-7 = [h1n_b(i-1) | h2_b(i-2)]   L2 inputs
// A-fragment reads row (lo&7): M rows 8-15 are read-time dups.
// Cell map (both roles, lane quad): quad0 -> L1 b0,b1 | quad1 -> L2 b0,b1
//   quad2 -> L1 b2,b3 | quad3 -> L2 b2,b3  (2 cells/lane, acc idx qoff+u)
// Pair p = w&7 owns h-cols p*16..p*16+15; role0 ct {p, p+8}, role1 {p+16, p+24}.
// h1n residual crosses quad0<->quad1, quad2<->quad3 via __shfl_xor(.,16),
// computed at loop BOTTOM (off the tail critical path).
// Double-buffered A, single-buffered ZX (safe: writes(i+1) after bar1(i+1),
// reads(i) before it), 2 barriers/iter, 1-step L1/L2 pipeline, 201 iters.

typedef __bf16 bf16_t;
typedef __bf16 bf16x8 __attribute__((ext_vector_type(8)));
typedef float f32x4 __attribute__((ext_vector_type(4)));

#define B_ 1024
#define T_ 200
#define D_ 128
#define G_ 512            // 4*D
#define RS 264            // A-tile row stride, bf16 elems

__global__ __launch_bounds__(1024, 4)
void lstm2_kernel(const float* __restrict__ x,
                  const float* __restrict__ W,
                  const float* __restrict__ U,
                  const float* __restrict__ bias,
                  float* __restrict__ out)
{
    __shared__ __align__(16) bf16_t A[2][8 * RS];        // 8448 B
    __shared__ __align__(16) float  ZX[8][4][2][16][2];  // 8192 B: [pair][quad][cell][lo][{si,sf}]

    const int tid  = threadIdx.x;
    const int w    = tid >> 6;           // wave 0..15
    const int role = w >> 3;             // 0: gates i,f | 1: gates g,o + state
    const int p    = w & 7;              // pair 0..7 -> h-cols p*16..p*16+15
    const int lane = tid & 63;
    const int lo   = lane & 15;
    const int quad = lane >> 4;
    const bool isL2 = (quad & 1);        // quads 1,3 -> layer-2 cells
    const bool hiB  = (quad >= 2);       // quads 2,3 -> batch rows 2,3
    const int  qoff = hiB ? 2 : 0;
    const int r0   = blockIdx.x * 4;     // 4 batch rows per block

    // zero A (h1(-1)=h2(-2)=h2(-1)=0; everything finite). ZX is always
    // written-before-read (iter 0 writes precede first read).
    {
        unsigned int* a32 = (unsigned int*)&A[0][0];
        for (int k = tid; k < 2 * 8 * RS / 2; k += 1024) a32[k] = 0u;
    }

    // ---- weight fragments: wave holds its 2 col-tiles only (64 VGPRs) ----
    // B-frag mfma_f32_16x16x32_bf16: lane holds B[k][n], n = 16*ct + lo,
    // k = 32*kt + quad*8 + jj; k<128 -> W, else U. ct = p + 8*c, c = role*2+t.
    // Pre-scaled: sig -> -log2e (i,f,o), tanh -> -2log2e (g).
    bf16x8 Breg[8][2];
    #pragma unroll
    for (int kt = 0; kt < 8; ++kt) {
        const int k0 = kt * 32 + quad * 8;
        #pragma unroll
        for (int t = 0; t < 2; ++t) {
            const int c = role * 2 + t;
            const float gs = (c == 2) ? -2.88539008177792681472f : -1.44269504088896340736f;
            const int n = (p + 8 * c) * 16 + lo;
            const float* src = (k0 < 128) ? (W + (size_t)k0 * G_ + n)
                                          : (U + (size_t)(k0 - 128) * G_ + n);
            bf16x8 v;
            #pragma unroll
            for (int jj = 0; jj < 8; ++jj) v[jj] = (bf16_t)(src[(size_t)jj * G_] * gs);
            Breg[kt][t] = v;
        }
    }

    // lane's h-column; pre-scaled biases as MFMA C-init (no per-iter adds/movs)
    const int col0 = p * 16 + lo;
    f32x4 binit[2];
    #pragma unroll
    for (int t = 0; t < 2; ++t) {
        const int c = role * 2 + t;
        const float gs = (c == 2) ? -2.88539008177792681472f : -1.44269504088896340736f;
        const float bs = bias[col0 + 128 * c] * gs;
        binit[t] = (f32x4){bs, bs, bs, bs};
    }

    // x staging: role-0 waves (tid<512), 1 f32 -> 1 bf16; row tid>>7, col tid&127
    const int xrow = (tid >> 7) & 3;
    const int xcol = tid & 127;
    const size_t xbase = (size_t)(r0 + xrow) * T_ * D_ + xcol;
    const int xdst = xrow * RS + xcol;
    float xv_hold = 0.f;
    if (role == 0) {
        A[0][xdst] = (bf16_t)x[xbase];                 // stage x(0)
        xv_hold = x[xbase + (size_t)D_];               // prefetch x(1)
    }

    float cst[2]   = {0.f, 0.f};   // role1: c1 (L1 lanes) / c2 (L2 lanes)
    float hsave[2] = {0.f, 0.f};   // role1: previous hnew
    float h1prev[2] = {0.f, 0.f};  // role1 L2 lanes: h1n(i-1), shfl'd at loop bottom

    const int fo = (lo & 7) * RS + quad * 8;   // A-fragment base (rows 8-15 dup at read)

    // out pointers (role1 L2 lanes, cells u=0,1 -> batch rows qoff+u)
    float* outp0 = out + (size_t)(r0 + qoff + 0) * T_ * D_ + col0;
    float* outp1 = out + (size_t)(r0 + qoff + 1) * T_ * D_ + col0;

    for (int i = 0; i <= T_; ++i) {
        // ---- barrier #1: A-tile(i) ready (lgkmcnt only, no vmcnt drain) ----
        asm volatile("s_waitcnt lgkmcnt(0)" ::: "memory");
        __builtin_amdgcn_s_barrier();
        asm volatile("" ::: "memory");
        __builtin_amdgcn_sched_barrier(0);

        const int pb = i & 1;
        const int nb = pb ^ 1;

        // ---- GEMM: 8 streamed fragment loads, 2 chained accumulators ----
        __builtin_amdgcn_s_setprio(1);
        bf16x8 af = *reinterpret_cast<const bf16x8*>(&A[pb][fo]);
        f32x4 acc0 = __builtin_amdgcn_mfma_f32_16x16x32_bf16(af, Breg[0][0], binit[0], 0, 0, 0);
        f32x4 acc1 = __builtin_amdgcn_mfma_f32_16x16x32_bf16(af, Breg[0][1], binit[1], 0, 0, 0);
        #pragma unroll
        for (int kt = 1; kt < 8; ++kt) {
            af = *reinterpret_cast<const bf16x8*>(&A[pb][fo + kt * 32]);
            acc0 = __builtin_amdgcn_mfma_f32_16x16x32_bf16(af, Breg[kt][0], acc0, 0, 0, 0);
            acc1 = __builtin_amdgcn_mfma_f32_16x16x32_bf16(af, Breg[kt][1], acc1, 0, 0, 0);
        }
        __builtin_amdgcn_s_setprio(0);

        // ---- pre-exchange trans (role-uniform branch; wave-uniform = cheap) ----
        float tg[2], so[2];
        if (role == 0) {
            // gates i (acc0), f (acc1): post sig(i), sig(f) to ZX
            #pragma unroll
            for (int u = 0; u < 2; ++u) {
                const int q = qoff + u;
                float zi = hiB ? acc0[q] : acc0[q];   // q already includes qoff
                float zf = acc1[q];
                float si = __builtin_amdgcn_rcpf(1.0f + __builtin_amdgcn_exp2f(zi));
                float sf = __builtin_amdgcn_rcpf(1.0f + __builtin_amdgcn_exp2f(zf));
                *reinterpret_cast<float2*>(&ZX[p][quad][u][lo][0]) = make_float2(si, sf);
            }
        } else {
            // gates g (acc0), o (acc1)
            #pragma unroll
            for (int u = 0; u < 2; ++u) {
                const int q = qoff + u;
                tg[u] = 2.0f * __builtin_amdgcn_rcpf(1.0f + __builtin_amdgcn_exp2f(acc0[q])) - 1.0f;
                so[u] = __builtin_amdgcn_rcpf(1.0f + __builtin_amdgcn_exp2f(acc1[q]));
            }
        }

        // ---- barrier #2: ZX(i) ready ----
        asm volatile("s_waitcnt lgkmcnt(0)" ::: "memory");
        __builtin_amdgcn_s_barrier();
        asm volatile("" ::: "memory");
        __builtin_amdgcn_sched_barrier(0);

        if (role == 0) {
            // post-exchange slot: x staging into next buffer + next prefetch
            if (i + 1 < T_)
                A[nb][xdst] = (bf16_t)xv_hold;
            if (i + 2 < T_)
                xv_hold = x[xbase + (size_t)(i + 2) * D_];
        } else {
            // serial state tail + all recurrent writes
            const bool upd = isL2 ? (i >= 1) : (i < T_);
            #pragma unroll
            for (int u = 0; u < 2; ++u) {
                float2 zz = *reinterpret_cast<const float2*>(&ZX[p][quad][u][lo][0]);
                float cn = zz.y * cst[u] + zz.x * tg[u];
                float tn = 2.0f * __builtin_amdgcn_rcpf(1.0f +
                             __builtin_amdgcn_exp2f(cn * -2.88539008177792681472f)) - 1.0f;
                float hn = so[u] * tn + (isL2 ? h1prev[u] : 0.0f);
                cst[u]   = upd ? cn : cst[u];
                hsave[u] = upd ? hn : 0.0f;   // 0 keeps LDS clean at edge steps
            }
            // h -> next A buffer (primary rows only)
            #pragma unroll
            for (int u = 0; u < 2; ++u) {
                const int b = qoff + u;
                const bf16_t hb = (bf16_t)hsave[u];
                if (!isL2) {
                    A[nb][b * RS + 128 + col0]       = hb;  // L1 recurrent
                    A[nb][(4 + b) * RS + col0]       = hb;  // L2 next input
                } else {
                    A[nb][(4 + b) * RS + 128 + col0] = hb;  // L2 recurrent
                }
            }
            // y(i-1) = h2n (includes residual); never drained at barriers
            if (i >= 1 && isL2) {
                outp0[(size_t)(i - 1) * D_] = hsave[0];
                outp1[(size_t)(i - 1) * D_] = hsave[1];
            }
            // h1n(i) -> L2 partner for next iter (off the tail critical path)
            h1prev[0] = __shfl_xor(hsave[0], 16, 64);
            h1prev[1] = __shfl_xor(hsave[1], 16, 64);
        }
    }
}

extern "C" void kernel_launch(void* const* d_in, const int* in_sizes, int n_in,
                              void* d_out, int out_size, void* d_ws, size_t ws_size,
                              hipStream_t stream) {
    const float* x = (const float*)d_in[0];
    const float* W = (const float*)d_in[1];
    const float* U = (const float*)d_in[2];
    const float* b = (const float*)d_in[3];
    // d_in[4] = seq_len (int32) — intentionally ignored, matching the reference.
    float* out = (float*)d_out;

    lstm2_kernel<<<dim3(B_ / 4), dim3(1024), 0, stream>>>(x, W, U, b, out);
}

// Round 5
// 367.460 us; speedup vs baseline: 1.0238x; 1.0238x over previous
//
#include <hip/hip_runtime.h>

// DynamicMultiRNN: 2-layer shared-weight LSTM, B=1024 T=200 D=128, residual on L2.
// f32 I/O, bf16 MFMA internals.
//
// R10 = R8 (best: 230 µs kernel) + PRIORITY-STAGGERED PHASES.
//  Model (fits R8 counters exactly): per SIMD per iter, MFMA pipe needs
//  2 waves x 32 x 19.4 cyc = 1242 (MfmaUtil 41% x 2746 ✓), VALU+trans ~1100
//  (41% ✓), and the phases SUM because both waves/SIMD run GEMM->gates in
//  lockstep (fair round-robin finishes both MFMA bursts at the same time).
//  Fix: wave w<4 (first on its SIMD) runs its MFMA burst at prio 2, partner
//  (w>=4) at prio 1. High wave owns the MFMA port, finishes at ~620, drops
//  prio and runs its gates on the VALU pipe WHILE the partner's burst owns
//  the MFMA pipe (620-1242). Pipes overlap instead of summing:
//  predicted wall 2746 -> ~1900-2100 cyc/iter.
//  R9's lesson applied: do NOT add waves/work — same structure, same traffic.
//  Micro: bias rides as first MFMA's C operand (kills 16 acc-init movs;
//  bit-identical accumulation order).
//
// PACKED A-TILE (8 x 256, RS=264), same as R8:
// rows 0-3 = [x_b(i)     | h1_b(i-1)]   L1 inputs, batch rows b=0..3
// rows 4-7 = [h1n_b(i-1) | h2_b(i-2)]   L2 inputs
// A-fragment reads row (lo&7): MFMA output rows 8-15 are read-time dups.
// Cell map: quad0 -> L1 b0,b1 | quad1 -> L2 b0,b1 | quad2 -> L1 b2,b3
//           quad3 -> L2 b2,b3  (2 cells/lane; hiB lanes select acc q+2)
// h1n residual crosses quad0<->quad1, quad2<->quad3 via __shfl_xor(.,16).
// Double-buffered A, single lgkm-only barrier/iter, 1-step L1/L2 pipeline,
// 201 iterations, 256 blocks x 512 threads.

typedef __bf16 bf16_t;
typedef __bf16 bf16x8 __attribute__((ext_vector_type(8)));
typedef float f32x4 __attribute__((ext_vector_type(4)));

#define B_ 1024
#define T_ 200
#define D_ 128
#define G_ 512            // 4*D
#define RS 264            // A-tile row stride, bf16 elems: 256 cols + 8 pad (528 B)

__global__ __launch_bounds__(512, 2)
void lstm2_kernel(const float* __restrict__ x,
                  const float* __restrict__ W,
                  const float* __restrict__ U,
                  const float* __restrict__ bias,
                  float* __restrict__ out)
{
    __shared__ __align__(16) bf16_t A[2][8 * RS];    // double-buffered packed tile

    const int tid  = threadIdx.x;
    const int w    = tid >> 6;           // wave 0..7; SIMD = w%4, pair = {w, w+4}
    const int lane = tid & 63;
    const int lo   = lane & 15;
    const int quad = lane >> 4;
    const bool isL2 = (quad & 1);        // quads 1,3 -> layer-2 cells
    const bool hiB  = (quad >= 2);       // quads 2,3 -> batch rows 2,3
    const int  qoff = hiB ? 2 : 0;
    const bool hiW  = (w < 4);           // first wave on each SIMD: MFMA-first role
    const int r0   = blockIdx.x * 4;     // 4 batch rows per block

    // zero both buffers (h1(-1)=h2(-2)=h2(-1)=0; everything finite)
    {
        unsigned int* a32 = (unsigned int*)&A[0][0];
        for (int k = tid; k < 2 * 8 * RS / 2; k += 512) a32[k] = 0u;
    }

    // ---- weight fragments (f32 -> bf16 regs), loaded once, reused 201x ----
    // B-frag mfma_f32_16x16x32_bf16: lane holds B[k][n], n = 16*ct + lo,
    // k = 32*kt + quad*8 + jj. k<128 -> W row k, else U row k-128.
    // Wave w's col-tiles ct = w + 8*c (c = gate i,f,g,o).
    // Weights pre-scaled: sig -> -log2e (i,f,o), tanh -> -2log2e (g).
    bf16x8 Breg[8][4];
    #pragma unroll
    for (int kt = 0; kt < 8; ++kt) {
        const int k0 = kt * 32 + quad * 8;
        #pragma unroll
        for (int c = 0; c < 4; ++c) {
            const float gs = (c == 2) ? -2.88539008177792681472f : -1.44269504088896340736f;
            const int n = (w + 8 * c) * 16 + lo;
            const float* src = (k0 < 128) ? (W + (size_t)k0 * G_ + n)
                                          : (U + (size_t)(k0 - 128) * G_ + n);
            bf16x8 v;
            #pragma unroll
            for (int jj = 0; jj < 8; ++jj) v[jj] = (bf16_t)(src[(size_t)jj * G_] * gs);
            Breg[kt][c] = v;
        }
    }

    // lane's gate column j; pre-scaled biases preloaded as first-MFMA C operand
    const int j = w * 16 + lo;
    f32x4 binit[4];
    #pragma unroll
    for (int c = 0; c < 4; ++c) {
        const float gs = (c == 2) ? -2.88539008177792681472f : -1.44269504088896340736f;
        const float bs = bias[j + 128 * c] * gs;
        binit[c] = (f32x4){bs, bs, bs, bs};
    }

    // x staging: 512 threads x 1 f32 -> 1 bf16; row = tid>>7 (0..3), col = tid&127
    const int xrow = tid >> 7;
    const int xcol = tid & 127;
    const size_t xbase = (size_t)(r0 + xrow) * T_ * D_ + xcol;
    const int xdst = xrow * RS + xcol;

    // stage x(0) into buffer 0; prefetch x(1) into a register (held one iter)
    A[0][xdst] = (bf16_t)x[xbase];
    float xv_hold = x[xbase + (size_t)D_];

    float cst[2]   = {0.f, 0.f};   // c1 (L1 lanes) or c2 (L2 lanes), per cell
    float hsave[2] = {0.f, 0.f};   // previous iter's hnew (persists across barrier)
    float h1prev[2];               // L2 lanes: h1n(i-1) f32, via shfl

    // A-fragment base: row (lo&7) -> lanes 8-15 broadcast-read rows 0-7
    const int fo = (lo & 7) * RS + quad * 8;

    // out pointers hoisted (used by L2 lanes only; cells q=0,1 -> rows qoff+q)
    float* outp0 = out + (size_t)(r0 + qoff + 0) * T_ * D_ + j;
    float* outp1 = out + (size_t)(r0 + qoff + 1) * T_ * D_ + j;

    for (int i = 0; i <= T_; ++i) {
        // ---- barrier WITHOUT vmcnt/expcnt drain (lgkmcnt only) ----
        asm volatile("s_waitcnt lgkmcnt(0)" ::: "memory");
        __builtin_amdgcn_s_barrier();
        asm volatile("" ::: "memory");
        __builtin_amdgcn_sched_barrier(0);

        const int pb = i & 1;
        const int nb = pb ^ 1;

        // x(i+1) -> next buffer, value loaded LAST iteration (latency hidden);
        // safe: A[nb] was fully read by iter i-1, barrier above closed those reads.
        if (i + 1 < T_)
            A[nb][xdst] = (bf16_t)xv_hold;
        // issue load of x(i+2), held until next iteration
        if (i + 2 < T_)
            xv_hold = x[xbase + (size_t)(i + 2) * D_];

        // h1n(i-1): L1 quad -> L2 quad partner (lane ^ 16)
        h1prev[0] = __shfl_xor(hsave[0], 16, 64);
        h1prev[1] = __shfl_xor(hsave[1], 16, 64);

        // ---- 8 fragment loads up front, then one packed GEMM ----
        // PRIO STAGGER: hiW wave bursts its 32 MFMAs at prio 2 (owns the MFMA
        // port, done ~620 cyc), partner at prio 1 follows (620-1242) while the
        // hiW wave's gates run on the VALU pipe -> pipes overlap, not sum.
        bf16x8 af[8];
        #pragma unroll
        for (int kt = 0; kt < 8; ++kt)
            af[kt] = *reinterpret_cast<const bf16x8*>(&A[pb][fo + kt * 32]);

        if (hiW) { __builtin_amdgcn_s_setprio(2); }
        else     { __builtin_amdgcn_s_setprio(1); }

        f32x4 acc[4];
        #pragma unroll
        for (int c = 0; c < 4; ++c)   // bias rides as first MFMA's C operand
            acc[c] = __builtin_amdgcn_mfma_f32_16x16x32_bf16(af[0], Breg[0][c], binit[c], 0, 0, 0);
        #pragma unroll
        for (int kt = 1; kt < 8; ++kt) {
            #pragma unroll
            for (int c = 0; c < 4; ++c)
                acc[c] = __builtin_amdgcn_mfma_f32_16x16x32_bf16(af[kt], Breg[kt][c], acc[c], 0, 0, 0);
        }
        __builtin_amdgcn_s_setprio(0);

        // ---- gates: 2 cells/lane; acc rows 8-15 are read-time dups, so hiB
        // lanes select q+2 (one v_cndmask per value, no cross-lane traffic) ----
        // L1 lanes active for i<T (step i); L2 lanes for i>=1 (step i-1)
        const bool upd = isL2 ? (i >= 1) : (i < T_);
        #pragma unroll
        for (int q = 0; q < 2; ++q) {
            float z0 = hiB ? acc[0][q + 2] : acc[0][q];
            float z1 = hiB ? acc[1][q + 2] : acc[1][q];
            float z2 = hiB ? acc[2][q + 2] : acc[2][q];
            float z3 = hiB ? acc[3][q + 2] : acc[3][q];
            float ig = __builtin_amdgcn_rcpf(1.0f + __builtin_amdgcn_exp2f(z0));
            float fg = __builtin_amdgcn_rcpf(1.0f + __builtin_amdgcn_exp2f(z1));
            float gg = 2.0f * __builtin_amdgcn_rcpf(1.0f + __builtin_amdgcn_exp2f(z2)) - 1.0f;
            float og = __builtin_amdgcn_rcpf(1.0f + __builtin_amdgcn_exp2f(z3));
            float cn = fg * cst[q] + ig * gg;
            float tn = 2.0f * __builtin_amdgcn_rcpf(1.0f +
                         __builtin_amdgcn_exp2f(cn * -2.88539008177792681472f)) - 1.0f;
            float hn = og * tn + (isL2 ? h1prev[q] : 0.0f);
            cst[q]   = upd ? cn : cst[q];
            hsave[q] = upd ? hn : 0.0f;   // 0 keeps LDS clean at edge steps
        }

        // ---- writes to next buffer (primary rows only — no dups) ----
        // Bank check: per store instr the 4 active quads hit rows {q,2+q,4+q,6+q}
        // or {4+q,6+q} -> disjoint 8-bank octets -> conflict-free.
        #pragma unroll
        for (int q = 0; q < 2; ++q) {
            const int b = qoff + q;              // batch row 0..3
            const bf16_t hb = (bf16_t)hsave[q];
            if (!isL2) {
                // h1n(b): L1 recurrent input (row b, cols 128-255)
                //         and L2 next input  (row 4+b, cols 0-127)
                A[nb][b * RS + 128 + j]       = hb;
                A[nb][(4 + b) * RS + j]       = hb;
            } else {
                // h2n(b): L2 recurrent input (row 4+b, cols 128-255)
                A[nb][(4 + b) * RS + 128 + j] = hb;
            }
        }

        // L2 lanes: emit y(i-1) = h2n (hsave includes the residual);
        // global stores are never drained at the barrier.
        if (i >= 1 && isL2) {
            outp0[(size_t)(i - 1) * D_] = hsave[0];
            outp1[(size_t)(i - 1) * D_] = hsave[1];
        }
    }
}

extern "C" void kernel_launch(void* const* d_in, const int* in_sizes, int n_in,
                              void* d_out, int out_size, void* d_ws, size_t ws_size,
                              hipStream_t stream) {
    const float* x = (const float*)d_in[0];
    const float* W = (const float*)d_in[1];
    const float* U = (const float*)d_in[2];
    const float* b = (const float*)d_in[3];
    // d_in[4] = seq_len (int32) — intentionally ignored, matching the reference.
    float* out = (float*)d_out;

    lstm2_kernel<<<dim3(B_ / 4), dim3(512), 0, stream>>>(x, W, U, b, out);
}

// Round 6
// 340.515 us; speedup vs baseline: 1.1049x; 1.0791x over previous
//
#include <hip/hip_runtime.h>

// DynamicMultiRNN: 2-layer shared-weight LSTM, B=1024 T=200 D=128, residual on L2.
// f32 I/O, bf16 MFMA internals.
//
// R11 = R8 (best: 230 µs kernel, 108 VGPR, no spill) + SPLIT-BURST INTERLEAVE.
//  R10's lesson: divergent setprio + C-operand rewrite -> spill (VGPR 128,
//  +36 MB scratch traffic) -> reverted. Same overlap goal, spill-safe route:
//  each wave's 32-MFMA burst is split into two 16-MFMA halves (acc0/acc1
//  chains, then acc2/acc3 chains) with the i/f-gate transcendentals BETWEEN.
//  In lockstep round-robin, wave A's trans section now issues while wave B's
//  MFMA chain owns the matrix pipe (and vice versa) -> trans hides under
//  MFMA instead of summing after it. No divergence, no extra registers,
//  bit-identical accumulation order per acc chain.
//
// PACKED A-TILE (8 x 256, RS=264), same as R8:
// rows 0-3 = [x_b(i)     | h1_b(i-1)]   L1 inputs, batch rows b=0..3
// rows 4-7 = [h1n_b(i-1) | h2_b(i-2)]   L2 inputs
// A-fragment reads row (lo&7): MFMA output rows 8-15 are read-time dups.
// Cell map: quad0 -> L1 b0,b1 | quad1 -> L2 b0,b1 | quad2 -> L1 b2,b3
//           quad3 -> L2 b2,b3  (2 cells/lane; hiB lanes select acc q+2)
// h1n residual crosses quad0<->quad1, quad2<->quad3 via __shfl_xor(.,16).
// Double-buffered A, single lgkm-only barrier/iter, 1-step L1/L2 pipeline,
// 201 iterations, 256 blocks x 512 threads.
// Known structural costs (measured, not worth chasing): 14.8M LDS "conflict"
// cycles = the 4-beat floor of 512 distinct B per wave-read through 32 banks;
// MFMA floor = 32 MFMA/wave (N_ct x K_kt), M-dup is free at instr level.

typedef __bf16 bf16_t;
typedef __bf16 bf16x8 __attribute__((ext_vector_type(8)));
typedef float f32x4 __attribute__((ext_vector_type(4)));

#define B_ 1024
#define T_ 200
#define D_ 128
#define G_ 512            // 4*D
#define RS 264            // A-tile row stride, bf16 elems: 256 cols + 8 pad (528 B)

__global__ __launch_bounds__(512, 2)
void lstm2_kernel(const float* __restrict__ x,
                  const float* __restrict__ W,
                  const float* __restrict__ U,
                  const float* __restrict__ bias,
                  float* __restrict__ out)
{
    __shared__ __align__(16) bf16_t A[2][8 * RS];    // double-buffered packed tile

    const int tid  = threadIdx.x;
    const int w    = tid >> 6;           // wave 0..7
    const int lane = tid & 63;
    const int lo   = lane & 15;
    const int quad = lane >> 4;
    const bool isL2 = (quad & 1);        // quads 1,3 -> layer-2 cells
    const bool hiB  = (quad >= 2);       // quads 2,3 -> batch rows 2,3
    const int  qoff = hiB ? 2 : 0;
    const int r0   = blockIdx.x * 4;     // 4 batch rows per block

    // zero both buffers (h1(-1)=h2(-2)=h2(-1)=0; everything finite)
    {
        unsigned int* a32 = (unsigned int*)&A[0][0];
        for (int k = tid; k < 2 * 8 * RS / 2; k += 512) a32[k] = 0u;
    }

    // ---- weight fragments (f32 -> bf16 regs), loaded once, reused 201x ----
    // B-frag mfma_f32_16x16x32_bf16: lane holds B[k][n], n = 16*ct + lo,
    // k = 32*kt + quad*8 + jj. k<128 -> W row k, else U row k-128.
    // Wave w's col-tiles ct = w + 8*c (c = gate i,f,g,o).
    // Weights pre-scaled: sig -> -log2e (i,f,o), tanh -> -2log2e (g).
    bf16x8 Breg[8][4];
    #pragma unroll
    for (int kt = 0; kt < 8; ++kt) {
        const int k0 = kt * 32 + quad * 8;
        #pragma unroll
        for (int c = 0; c < 4; ++c) {
            const float gs = (c == 2) ? -2.88539008177792681472f : -1.44269504088896340736f;
            const int n = (w + 8 * c) * 16 + lo;
            const float* src = (k0 < 128) ? (W + (size_t)k0 * G_ + n)
                                          : (U + (size_t)(k0 - 128) * G_ + n);
            bf16x8 v;
            #pragma unroll
            for (int jj = 0; jj < 8; ++jj) v[jj] = (bf16_t)(src[(size_t)jj * G_] * gs);
            Breg[kt][c] = v;
        }
    }

    // lane's gate column j; pre-scaled biases preloaded into acc init
    const int j = w * 16 + lo;
    f32x4 binit[4];
    #pragma unroll
    for (int c = 0; c < 4; ++c) {
        const float gs = (c == 2) ? -2.88539008177792681472f : -1.44269504088896340736f;
        const float bs = bias[j + 128 * c] * gs;
        binit[c] = (f32x4){bs, bs, bs, bs};
    }

    // x staging: 512 threads x 1 f32 -> 1 bf16; row = tid>>7 (0..3), col = tid&127
    const int xrow = tid >> 7;
    const int xcol = tid & 127;
    const size_t xbase = (size_t)(r0 + xrow) * T_ * D_ + xcol;
    const int xdst = xrow * RS + xcol;

    // stage x(0) into buffer 0; prefetch x(1) into a register (held one iter)
    A[0][xdst] = (bf16_t)x[xbase];
    float xv_hold = x[xbase + (size_t)D_];

    float cst[2]   = {0.f, 0.f};   // c1 (L1 lanes) or c2 (L2 lanes), per cell
    float hsave[2] = {0.f, 0.f};   // previous iter's hnew (persists across barrier)
    float h1prev[2];               // L2 lanes: h1n(i-1) f32, via shfl

    // A-fragment base: row (lo&7) -> lanes 8-15 broadcast-read rows 0-7
    const int fo = (lo & 7) * RS + quad * 8;

    // out pointers hoisted (used by L2 lanes only; cells q=0,1 -> rows qoff+q)
    float* outp0 = out + (size_t)(r0 + qoff + 0) * T_ * D_ + j;
    float* outp1 = out + (size_t)(r0 + qoff + 1) * T_ * D_ + j;

    for (int i = 0; i <= T_; ++i) {
        // ---- barrier WITHOUT vmcnt/expcnt drain (lgkmcnt only) ----
        asm volatile("s_waitcnt lgkmcnt(0)" ::: "memory");
        __builtin_amdgcn_s_barrier();
        asm volatile("" ::: "memory");
        __builtin_amdgcn_sched_barrier(0);

        const int pb = i & 1;
        const int nb = pb ^ 1;

        // x(i+1) -> next buffer, value loaded LAST iteration (latency hidden);
        // safe: A[nb] was fully read by iter i-1, barrier above closed those reads.
        if (i + 1 < T_)
            A[nb][xdst] = (bf16_t)xv_hold;
        // issue load of x(i+2), held until next iteration
        if (i + 2 < T_)
            xv_hold = x[xbase + (size_t)(i + 2) * D_];

        // h1n(i-1): L1 quad -> L2 quad partner (lane ^ 16)
        h1prev[0] = __shfl_xor(hsave[0], 16, 64);
        h1prev[1] = __shfl_xor(hsave[1], 16, 64);

        // ---- 8 fragment loads up front ----
        bf16x8 af[8];
        #pragma unroll
        for (int kt = 0; kt < 8; ++kt)
            af[kt] = *reinterpret_cast<const bf16x8*>(&A[pb][fo + kt * 32]);

        // ---- HALF 1: i,f-gate accumulator chains (16 MFMA) ----
        f32x4 acc0 = binit[0];
        f32x4 acc1 = binit[1];
        __builtin_amdgcn_s_setprio(1);
        #pragma unroll
        for (int kt = 0; kt < 8; ++kt) {
            acc0 = __builtin_amdgcn_mfma_f32_16x16x32_bf16(af[kt], Breg[kt][0], acc0, 0, 0, 0);
            acc1 = __builtin_amdgcn_mfma_f32_16x16x32_bf16(af[kt], Breg[kt][1], acc1, 0, 0, 0);
        }
        __builtin_amdgcn_s_setprio(0);

        // ---- MID: i,f transcendentals — issue while the partner wave's (and
        // our own upcoming) g,o chains occupy the MFMA pipe ----
        float ig[2], fg[2];
        #pragma unroll
        for (int q = 0; q < 2; ++q) {
            float z0 = hiB ? acc0[q + 2] : acc0[q];
            float z1 = hiB ? acc1[q + 2] : acc1[q];
            ig[q] = __builtin_amdgcn_rcpf(1.0f + __builtin_amdgcn_exp2f(z0));
            fg[q] = __builtin_amdgcn_rcpf(1.0f + __builtin_amdgcn_exp2f(z1));
        }

        // ---- HALF 2: g,o-gate accumulator chains (16 MFMA) ----
        f32x4 acc2 = binit[2];
        f32x4 acc3 = binit[3];
        __builtin_amdgcn_s_setprio(1);
        #pragma unroll
        for (int kt = 0; kt < 8; ++kt) {
            acc2 = __builtin_amdgcn_mfma_f32_16x16x32_bf16(af[kt], Breg[kt][2], acc2, 0, 0, 0);
            acc3 = __builtin_amdgcn_mfma_f32_16x16x32_bf16(af[kt], Breg[kt][3], acc3, 0, 0, 0);
        }
        __builtin_amdgcn_s_setprio(0);

        // ---- remaining gates + state update + stores, per cell ----
        // L1 lanes active for i<T (step i); L2 lanes for i>=1 (step i-1)
        const bool upd = isL2 ? (i >= 1) : (i < T_);
        #pragma unroll
        for (int q = 0; q < 2; ++q) {
            float z2 = hiB ? acc2[q + 2] : acc2[q];
            float z3 = hiB ? acc3[q + 2] : acc3[q];
            float gg = 2.0f * __builtin_amdgcn_rcpf(1.0f + __builtin_amdgcn_exp2f(z2)) - 1.0f;
            float og = __builtin_amdgcn_rcpf(1.0f + __builtin_amdgcn_exp2f(z3));
            float cn = fg[q] * cst[q] + ig[q] * gg;
            float tn = 2.0f * __builtin_amdgcn_rcpf(1.0f +
                         __builtin_amdgcn_exp2f(cn * -2.88539008177792681472f)) - 1.0f;
            float hn = og * tn + (isL2 ? h1prev[q] : 0.0f);
            cst[q]   = upd ? cn : cst[q];
            hsave[q] = upd ? hn : 0.0f;   // 0 keeps LDS clean at edge steps

            // stores for this cell as soon as it's final
            const int b = qoff + q;              // batch row 0..3
            const bf16_t hb = (bf16_t)hsave[q];
            if (!isL2) {
                // h1n(b): L1 recurrent input (row b, cols 128-255)
                //         and L2 next input  (row 4+b, cols 0-127)
                A[nb][b * RS + 128 + j]       = hb;
                A[nb][(4 + b) * RS + j]       = hb;
            } else {
                // h2n(b): L2 recurrent input (row 4+b, cols 128-255)
                A[nb][(4 + b) * RS + 128 + j] = hb;
            }
        }

        // L2 lanes: emit y(i-1) = h2n (hsave includes the residual);
        // global stores are never drained at the barrier.
        if (i >= 1 && isL2) {
            outp0[(size_t)(i - 1) * D_] = hsave[0];
            outp1[(size_t)(i - 1) * D_] = hsave[1];
        }
    }
}

extern "C" void kernel_launch(void* const* d_in, const int* in_sizes, int n_in,
                              void* d_out, int out_size, void* d_ws, size_t ws_size,
                              hipStream_t stream) {
    const float* x = (const float*)d_in[0];
    const float* W = (const float*)d_in[1];
    const float* U = (const float*)d_in[2];
    const float* b = (const float*)d_in[3];
    // d_in[4] = seq_len (int32) — intentionally ignored, matching the reference.
    float* out = (float*)d_out;

    lstm2_kernel<<<dim3(B_ / 4), dim3(512), 0, stream>>>(x, W, U, b, out);
}

// Round 7
// 325.302 us; speedup vs baseline: 1.1565x; 1.0468x over previous
//
#include <hip/hip_runtime.h>

// DynamicMultiRNN: 2-layer shared-weight LSTM, B=1024 T=200 D=128, residual on L2.
// f32 I/O, bf16 MFMA internals.
//
// R12 = R8 (best: 230 µs) + VALU-phase diet. Model: wall = MFMA phase (1242
// cyc/SIMD, hard floor) + gate/VALU phase (~1100) + ~400 sync, phases SUM due
// to recurrence + lockstep waves (anti-phasing failed 3x: R9/R10/R11). This
// round shrinks the VALU phase only:
//  (1) ROW-PERMUTED A-tile: phys rows {L1b0,L1b1,L2b0,L2b1,L1b2,L1b3,L2b2,
//      L2b3}; fragment M-row lo reads phys ((lo>>2)<<1)|(lo&1), so every
//      quad's 2 cells land at acc q=0,1 -> all 8 dup-select cndmasks gone.
//      Same row set + same 32-address read pattern -> bank behavior identical.
//  (2) bias rides as C operand of the kt=0 MFMAs -> 16 acc-init movs gone.
//  (3) edge guards peeled: first iteration (i=0) zeroes L2 state once;
//      i=T needs no guard (its writes are never read, values finite) ->
//      4 'upd' cndmasks gone from 201 iterations.
//  (4) unroll x2 (compile-time buffer parity) + precomputed LDS store offsets
//      -> addressing folds to reg+immediate, ~10 v_adds/iter gone.
// Gate math/order unchanged -> bit-identical output vs R8.
//
// PACKED A-TILE (8 x 256, RS=264), permuted rows:
// phys 0,1 = L1 b0,b1   [x | h1]      phys 2,3 = L2 b0,b1   [h1n | h2]
// phys 4,5 = L1 b2,b3                 phys 6,7 = L2 b2,b3
// Cell map (unchanged): quad0 -> L1 b0,b1 | quad1 -> L2 b0,b1
//                       quad2 -> L1 b2,b3 | quad3 -> L2 b2,b3
// h1n residual crosses quad pairs via __shfl_xor(.,16).
// Double-buffered A, single lgkm-only barrier/iter, 1-step L1/L2 pipeline,
// 201 iterations, 256 blocks x 512 threads.
// Known structural floors (measured): 256 MFMA/CU/iter (N x K tiling, M-pad
// free at instr level); 14.8M LDS conflict cyc = 4-beat floor of 512 B/wave
// fragment reads; HBM ~25 µs total (not a factor).

typedef __bf16 bf16_t;
typedef __bf16 bf16x8 __attribute__((ext_vector_type(8)));
typedef float f32x4 __attribute__((ext_vector_type(4)));

#define B_ 1024
#define T_ 200
#define D_ 128
#define G_ 512            // 4*D
#define RS 264            // A-tile row stride, bf16 elems: 256 cols + 8 pad (528 B)

__global__ __launch_bounds__(512, 2)
void lstm2_kernel(const float* __restrict__ x,
                  const float* __restrict__ W,
                  const float* __restrict__ U,
                  const float* __restrict__ bias,
                  float* __restrict__ out)
{
    __shared__ __align__(16) bf16_t A[2][8 * RS];    // double-buffered packed tile

    const int tid  = threadIdx.x;
    const int w    = tid >> 6;           // wave 0..7
    const int lane = tid & 63;
    const int lo   = lane & 15;
    const int quad = lane >> 4;
    const bool isL2 = (quad & 1);        // quads 1,3 -> layer-2 cells
    const int  qoff = (quad >= 2) ? 2 : 0;
    const int r0   = blockIdx.x * 4;     // 4 batch rows per block

    // zero both buffers (h1(-1)=h2(-2)=h2(-1)=0; everything finite)
    {
        unsigned int* a32 = (unsigned int*)&A[0][0];
        for (int k = tid; k < 2 * 8 * RS / 2; k += 512) a32[k] = 0u;
    }

    // ---- weight fragments (f32 -> bf16 regs), loaded once, reused 201x ----
    // B-frag mfma_f32_16x16x32_bf16: lane holds B[k][n], n = 16*ct + lo,
    // k = 32*kt + quad*8 + jj. k<128 -> W row k, else U row k-128.
    // Wave w's col-tiles ct = w + 8*c (c = gate i,f,g,o).
    // Weights pre-scaled: sig -> -log2e (i,f,o), tanh -> -2log2e (g).
    bf16x8 Breg[8][4];
    #pragma unroll
    for (int kt = 0; kt < 8; ++kt) {
        const int k0 = kt * 32 + quad * 8;
        #pragma unroll
        for (int c = 0; c < 4; ++c) {
            const float gs = (c == 2) ? -2.88539008177792681472f : -1.44269504088896340736f;
            const int n = (w + 8 * c) * 16 + lo;
            const float* src = (k0 < 128) ? (W + (size_t)k0 * G_ + n)
                                          : (U + (size_t)(k0 - 128) * G_ + n);
            bf16x8 v;
            #pragma unroll
            for (int jj = 0; jj < 8; ++jj) v[jj] = (bf16_t)(src[(size_t)jj * G_] * gs);
            Breg[kt][c] = v;
        }
    }

    // lane's gate column j; pre-scaled biases ride as C of the kt=0 MFMAs
    const int j = w * 16 + lo;
    f32x4 binit[4];
    #pragma unroll
    for (int c = 0; c < 4; ++c) {
        const float gs = (c == 2) ? -2.88539008177792681472f : -1.44269504088896340736f;
        const float bs = bias[j + 128 * c] * gs;
        binit[c] = (f32x4){bs, bs, bs, bs};
    }

    // x staging: 512 threads x 1 f32 -> 1 bf16; batch row = tid>>7, col = tid&127
    const int xb   = tid >> 7;                       // batch row 0..3
    const int xcol = tid & 127;
    const int xrowp = ((xb >> 1) << 2) | (xb & 1);   // phys L1 row of batch xb
    const size_t xbase = (size_t)(r0 + xb) * T_ * D_ + xcol;
    const int xdst = xrowp * RS + xcol;

    // stage x(0) into buffer 0; prefetch x(1) into a register (held one iter)
    A[0][xdst] = (bf16_t)x[xbase];
    float xv_hold = x[xbase + (size_t)D_];

    float cst[2]   = {0.f, 0.f};   // c1 (L1 lanes) or c2 (L2 lanes), per cell
    float hsave[2] = {0.f, 0.f};   // previous iter's hnew (persists across barrier)

    // A-fragment base: M-row lo -> phys row ((lo>>2)<<1)|(lo&1)
    const int frow = ((lo >> 2) << 1) | (lo & 1);
    const int fo = frow * RS + quad * 8;

    // precomputed LDS store offsets (element units) for this lane's 2 cells
    int wA[2], wB[2];
    #pragma unroll
    for (int q = 0; q < 2; ++q) {
        const int b = qoff + q;                          // batch row 0..3
        const int l1row = ((b >> 1) << 2) | (b & 1);     // phys L1 row
        const int l2row = l1row + 2;                     // phys L2 row
        // L1 lanes: recurrent h1 (l1row, cols 128+) and L2-input (l2row, cols 0+)
        // L2 lanes: recurrent h2 (l2row, cols 128+)
        wA[q] = isL2 ? (l2row * RS + 128 + j) : (l1row * RS + 128 + j);
        wB[q] = l2row * RS + j;                          // used by L1 lanes only
    }

    // out pointers hoisted (used by L2 lanes only; cells q=0,1 -> rows qoff+q)
    float* outp0 = out + (size_t)(r0 + qoff + 0) * T_ * D_ + j;
    float* outp1 = out + (size_t)(r0 + qoff + 1) * T_ * D_ + j;

    // One iteration body. PB/NB are literal buffer indices (compile-time LDS
    // bases); FIRST=1 only for the peeled i=0 body (L2 state zeroing).
#define BODY(I, PB, NB, FIRST)                                                    \
    do {                                                                          \
        /* barrier WITHOUT vmcnt/expcnt drain (lgkmcnt only) */                   \
        asm volatile("s_waitcnt lgkmcnt(0)" ::: "memory");                        \
        __builtin_amdgcn_s_barrier();                                             \
        asm volatile("" ::: "memory");                                            \
        __builtin_amdgcn_sched_barrier(0);                                        \
        /* x(i+1) -> next buffer (value loaded last iter); prefetch x(i+2) */     \
        if ((I) + 1 < T_) A[NB][xdst] = (bf16_t)xv_hold;                          \
        if ((I) + 2 < T_) xv_hold = x[xbase + (size_t)((I) + 2) * D_];            \
        /* h1n(i-1) across quad pairs; zeroed for L1 lanes (residual add) */      \
        float h1p0 = __shfl_xor(hsave[0], 16, 64);                                \
        float h1p1 = __shfl_xor(hsave[1], 16, 64);                                \
        h1p0 = isL2 ? h1p0 : 0.0f;                                                \
        h1p1 = isL2 ? h1p1 : 0.0f;                                                \
        /* 8 fragment loads up front, then one packed GEMM (4 chains) */          \
        bf16x8 af[8];                                                             \
        _Pragma("unroll")                                                         \
        for (int kt = 0; kt < 8; ++kt)                                            \
            af[kt] = *reinterpret_cast<const bf16x8*>(&A[PB][fo + kt * 32]);      \
        f32x4 acc[4];                                                             \
        __builtin_amdgcn_s_setprio(1);                                            \
        _Pragma("unroll")                                                         \
        for (int c = 0; c < 4; ++c)   /* bias as C operand: no init movs */       \
            acc[c] = __builtin_amdgcn_mfma_f32_16x16x32_bf16(af[0], Breg[0][c], binit[c], 0, 0, 0); \
        _Pragma("unroll")                                                         \
        for (int kt = 1; kt < 8; ++kt) {                                          \
            _Pragma("unroll")                                                     \
            for (int c = 0; c < 4; ++c)                                           \
                acc[c] = __builtin_amdgcn_mfma_f32_16x16x32_bf16(af[kt], Breg[kt][c], acc[c], 0, 0, 0); \
        }                                                                         \
        __builtin_amdgcn_s_setprio(0);                                            \
        /* gates: 2 cells/lane at acc q=0,1 (row permute: no dup selects) */      \
        _Pragma("unroll")                                                         \
        for (int q = 0; q < 2; ++q) {                                             \
            float ig = __builtin_amdgcn_rcpf(1.0f + __builtin_amdgcn_exp2f(acc[0][q])); \
            float fg = __builtin_amdgcn_rcpf(1.0f + __builtin_amdgcn_exp2f(acc[1][q])); \
            float gg = 2.0f * __builtin_amdgcn_rcpf(1.0f + __builtin_amdgcn_exp2f(acc[2][q])) - 1.0f; \
            float og = __builtin_amdgcn_rcpf(1.0f + __builtin_amdgcn_exp2f(acc[3][q])); \
            float cn = fg * cst[q] + ig * gg;                                     \
            float tn = 2.0f * __builtin_amdgcn_rcpf(1.0f +                        \
                         __builtin_amdgcn_exp2f(cn * -2.88539008177792681472f)) - 1.0f; \
            float hn = og * tn + ((q) ? h1p1 : h1p0);                             \
            cst[q]   = cn;                                                        \
            hsave[q] = hn;                                                        \
        }                                                                         \
        if (FIRST) { /* peeled i=0: L2 step is junk; c2(-1)=h2(-1)=0 */           \
            cst[0]   = isL2 ? 0.0f : cst[0];                                      \
            cst[1]   = isL2 ? 0.0f : cst[1];                                      \
            hsave[0] = isL2 ? 0.0f : hsave[0];                                    \
            hsave[1] = isL2 ? 0.0f : hsave[1];                                    \
        }                                                                         \
        /* writes to next buffer (precomputed offsets, reg+imm addressing) */     \
        _Pragma("unroll")                                                         \
        for (int q = 0; q < 2; ++q) {                                             \
            const bf16_t hb = (bf16_t)hsave[q];                                   \
            A[NB][wA[q]] = hb;                                                    \
            if (!isL2) A[NB][wB[q]] = hb;                                         \
        }                                                                         \
        /* y(i-1) = h2n (includes residual); never drained at the barrier */      \
        if ((I) >= 1 && isL2) {                                                   \
            outp0[(size_t)((I) - 1) * D_] = hsave[0];                             \
            outp1[(size_t)((I) - 1) * D_] = hsave[1];                             \
        }                                                                         \
    } while (0)

    // peeled i=0 (pb=0), then 100 unrolled pairs: (1,2),(3,4),...,(199,200)
    BODY(0, 0, 1, 1);
    for (int i = 1; i < T_; i += 2) {
        BODY(i,     1, 0, 0);
        BODY(i + 1, 0, 1, 0);
    }
#undef BODY
}

extern "C" void kernel_launch(void* const* d_in, const int* in_sizes, int n_in,
                              void* d_out, int out_size, void* d_ws, size_t ws_size,
                              hipStream_t stream) {
    const float* x = (const float*)d_in[0];
    const float* W = (const float*)d_in[1];
    const float* U = (const float*)d_in[2];
    const float* b = (const float*)d_in[3];
    // d_in[4] = seq_len (int32) — intentionally ignored, matching the reference.
    float* out = (float*)d_out;

    lstm2_kernel<<<dim3(B_ / 4), dim3(512), 0, stream>>>(x, W, U, b, out);
}